// Round 8
// baseline (158.376 us; speedup 1.0000x reference)
//
#include <hip/hip_runtime.h>
#include <hip/hip_bf16.h>

// LearnableDiffusionContrastiveLoss on MI355X.
// Algebra: l2norm(dm_normalized @ z) == l2norm(dm @ z) (positive row scaling
// cancels) -> skip the 10-step normalization entirely.
// R8: L2-residency fix. ks = blockIdx%8 -> each XCD (round-robin dispatch)
// handles ONE K-split slice: its zp slice (512KB) stays L2-resident and B
// staging runs at L2 BW. dm loads + part stores are NON-TEMPORAL so the
// 256MB stream can't evict L2. LDS layouts [row][32k]/[col][32k]: all
// ds traffic contiguous per 64-lane group -> conflict-free.

typedef float f32x4 __attribute__((ext_vector_type(4)));
typedef short s16x8 __attribute__((ext_vector_type(8)));

#define NN 8192
#define DFF 256
#define NNEG 10

__device__ __forceinline__ unsigned short f2bf(float x) {
  return __builtin_bit_cast(unsigned short, __float2bfloat16(x));
}

__device__ __forceinline__ float bf2f(unsigned short u) {
  return __builtin_bit_cast(float, (unsigned int)u << 16);
}

__device__ __forceinline__ void gload_lds16(const void* g, void* l) {
  __builtin_amdgcn_global_load_lds(
      (const __attribute__((address_space(1))) void*)(void*)g,
      (__attribute__((address_space(3))) void*)l, 16, 0, 0);
}

__device__ __forceinline__ float dot4(float4 a, float4 b) {
  return a.x * b.x + a.y * b.y + a.z * b.z + a.w * b.w;
}

// ---- pack z [8192][256] f32 -> zp bf16 [chunk 256][d 256][kk 32] -------------
// zp elem offset(k,d) = (k>>5)*8192 + d*32 + (k&31): each GEMM K-step tile
// (32 k x 256 d) is one contiguous 16KB chunk, d-major (matches sB layout).
__global__ void k_pack(const float* __restrict__ z,
                       unsigned short* __restrict__ zp) {
  __shared__ float tile[64][65];
  const int bx = blockIdx.x;  // k tile 0..127
  const int by = blockIdx.y;  // d tile 0..3
  const int t = threadIdx.x;
  const int lc = t & 63, lq = t >> 6;  // 0..3
#pragma unroll
  for (int p = 0; p < 16; ++p) {
    const int kr = lq * 16 + p;
    tile[kr][lc] = z[(size_t)(bx * 64 + kr) * DFF + by * 64 + lc];
  }
  __syncthreads();
  const int c2 = lq >> 1;  // chunk within tile
  const int q = lq & 1;    // k-half (16)
  s16x8 v0, v1;
#pragma unroll
  for (int ke = 0; ke < 8; ++ke)
    v0[ke] = (short)f2bf(tile[c2 * 32 + q * 16 + ke][lc]);
#pragma unroll
  for (int ke = 0; ke < 8; ++ke)
    v1[ke] = (short)f2bf(tile[c2 * 32 + q * 16 + 8 + ke][lc]);
  unsigned short* dst =
      zp + (size_t)(bx * 2 + c2) * 8192 + (by * 64 + lc) * 32 + q * 16;
  *(s16x8*)dst = v0;
  *(s16x8*)(dst + 8) = v1;
}

// ---- GEMM: part[ks] = dm[mtile, ks-slice] @ z  (BM=128, BN=256, BK=32) -------
// 512 thr / 8 waves, wave (wm,wn)=(w>>2,w&3) owns rows [wm*64,+64) x cols
// [wn*64,+64): 4x4 16x16x32 frags. LDS dbuf 48KB:
//   sA: [row 128][kk 32] bf16 8KB (nt f32 loads -> bf16 -> linear ds_write)
//   sB: [d 256][kk 32] bf16 16KB (= zp chunk, byte-linear gload_lds)
// All LDS ops contiguous 1KB per 64-lane group -> conflict-free.
__global__ __launch_bounds__(512, 2) void k_gemm(const float* __restrict__ dm,
                                                 const unsigned short* __restrict__ zp,
                                                 unsigned short* __restrict__ part,
                                                 int KS) {
  __shared__ __align__(16) unsigned short sA[2][4096];  // 2 x 8 KB
  __shared__ __align__(16) unsigned short sB[2][8192];  // 2 x 16 KB
  const int bx = blockIdx.x;
  const int ks = bx & (KS - 1);  // == XCD id when KS=8 (round-robin dispatch)
  const int mtile = bx / KS;     // 0..63
  const int klen = NN / KS;
  const int k0 = ks * klen;
  const int c0 = k0 >> 5;       // first K-chunk
  const int steps = klen / 32;  // 32 for KS=8
  const int tid = threadIdx.x;
  const int w = tid >> 6;
  const int l = tid & 63;
  const int m0 = mtile * 128;

  // A staging: thread owns 8 consecutive k of one row (2 nt float4 -> 1 s16x8)
  const int arow = w * 16 + (l & 15);  // 0..127
  const int akw = l >> 4;              // 0..3
  const float* asrc = dm + (size_t)(m0 + arow) * NN + k0 + akw * 8;

  const int r16 = l & 15, kw = l >> 4;
  const int wm = w >> 2, wn = w & 3;

  f32x4 acc[4][4] = {};
  f32x4 a0, a1;

#define LOAD_A(t_)                                                            \
  {                                                                           \
    a0 = __builtin_nontemporal_load((const f32x4*)(asrc + (t_)*32));          \
    a1 = __builtin_nontemporal_load((const f32x4*)(asrc + (t_)*32 + 4));      \
  }

#define WRITE_A(s_)                                                          \
  {                                                                          \
    s16x8 h_;                                                                \
    h_[0] = (short)f2bf(a0[0]); h_[1] = (short)f2bf(a0[1]);                  \
    h_[2] = (short)f2bf(a0[2]); h_[3] = (short)f2bf(a0[3]);                  \
    h_[4] = (short)f2bf(a1[0]); h_[5] = (short)f2bf(a1[1]);                  \
    h_[6] = (short)f2bf(a1[2]); h_[7] = (short)f2bf(a1[3]);                  \
    *(s16x8*)&sA[s_][arow * 32 + akw * 8] = h_;                              \
  }

#define STAGE_B(t_, s_)                                                      \
  {                                                                          \
    const unsigned short* cs_ = zp + (size_t)(c0 + (t_)) * 8192;             \
    _Pragma("unroll") for (int q = 0; q < 2; ++q) {                          \
      const int piece_ = w * 2 + q; /* 0..15, 1KB each */                    \
      gload_lds16((const char*)(cs_ + piece_ * 512) + l * 16,                \
                  (char*)sB[s_] + piece_ * 1024);                            \
    }                                                                        \
  }

#define COMPUTE(s_)                                                          \
  {                                                                          \
    s16x8 af[4], bfr[4];                                                     \
    _Pragma("unroll") for (int mi = 0; mi < 4; ++mi) {                       \
      const int row_ = wm * 64 + mi * 16 + r16;                              \
      af[mi] = *(const s16x8*)&sA[s_][row_ * 32 + kw * 8];                   \
    }                                                                        \
    _Pragma("unroll") for (int nj = 0; nj < 4; ++nj) {                       \
      const int col_ = wn * 64 + nj * 16 + r16;                              \
      bfr[nj] = *(const s16x8*)&sB[s_][col_ * 32 + kw * 8];                  \
    }                                                                        \
    _Pragma("unroll") for (int mi = 0; mi < 4; ++mi)                         \
      _Pragma("unroll") for (int nj = 0; nj < 4; ++nj)                       \
        acc[mi][nj] = __builtin_amdgcn_mfma_f32_16x16x32_bf16(               \
            af[mi], bfr[nj], acc[mi][nj], 0, 0, 0);                          \
  }

  // prologue
  STAGE_B(0, 0);
  LOAD_A(0);
  WRITE_A(0);
  __syncthreads();

  for (int t = 0; t < steps; ++t) {
    const int cur = t & 1, nxt = cur ^ 1;
    if (t + 1 < steps) {
      LOAD_A(t + 1);
      STAGE_B(t + 1, nxt);
    }
    COMPUTE(cur);
    if (t + 1 < steps) WRITE_A(nxt);
    __syncthreads();
  }

#undef LOAD_A
#undef WRITE_A
#undef STAGE_B
#undef COMPUTE

  // epilogue: C/D layout col=lane&15, row=(lane>>4)*4+reg [verified m89/m91]
  unsigned short* cb = part + (size_t)ks * NN * DFF;
#pragma unroll
  for (int mi = 0; mi < 4; ++mi)
#pragma unroll
    for (int nj = 0; nj < 4; ++nj) {
      const int col = wn * 64 + nj * 16 + r16;
      const int row0 = m0 + wm * 64 + mi * 16 + kw * 4;
#pragma unroll
      for (int r = 0; r < 4; ++r)
        __builtin_nontemporal_store(
            f2bf(acc[mi][nj][r]), cb + (size_t)(row0 + r) * DFF + col);
    }
}

// ---- fused loss: neg norms, K-split partial sum (bf16), norms, LSE -----------
__global__ __launch_bounds__(256) void k_loss(const float* __restrict__ z,
                                              const unsigned short* __restrict__ part,
                                              const int* __restrict__ neg_idx,
                                              float* __restrict__ lpart, int KS) {
  __shared__ float sneg[NNEG * DFF];
  __shared__ float swsum[4];
  const int t = threadIdx.x;
  const int w = t >> 6, l = t & 63;
  for (int k = w; k < NNEG; k += 4) {
    const int idx = neg_idx[k];
    float4 v = *(const float4*)(z + (size_t)idx * DFF + l * 4);
    float ss = dot4(v, v);
#pragma unroll
    for (int off = 32; off > 0; off >>= 1) ss += __shfl_xor(ss, off);
    const float s = 1.0f / fmaxf(sqrtf(ss), 1e-12f);
    float4 o;
    o.x = v.x * s; o.y = v.y * s; o.z = v.z * s; o.w = v.w * s;
    *(float4*)&sneg[k * DFF + l * 4] = o;
  }
  __syncthreads();
  const int gw = blockIdx.x * 4 + w;  // 0..1023, 8 rows each
  float lsum = 0.f;
  for (int rr = 0; rr < 8; ++rr) {
    const int i = gw * 8 + rr;
    const float4 a = *(const float4*)(z + (size_t)i * DFF + l * 4);
    float4 p; p.x = 0.f; p.y = 0.f; p.z = 0.f; p.w = 0.f;
    for (int ksp = 0; ksp < KS; ++ksp) {
      const ushort4 q =
          *(const ushort4*)(part + ((size_t)ksp * NN + i) * DFF + l * 4);
      p.x += bf2f(q.x); p.y += bf2f(q.y); p.z += bf2f(q.z); p.w += bf2f(q.w);
    }
    float vals[13];
    vals[0] = dot4(a, a);
    vals[1] = dot4(p, p);
    vals[2] = dot4(a, p);
#pragma unroll
    for (int k = 0; k < NNEG; ++k) {
      const float4 nv = *(const float4*)&sneg[k * DFF + l * 4];
      vals[3 + k] = dot4(a, nv);
    }
#pragma unroll
    for (int off = 32; off > 0; off >>= 1)
#pragma unroll
      for (int j = 0; j < 13; ++j) vals[j] += __shfl_xor(vals[j], off);
    const float na = fmaxf(sqrtf(vals[0]), 1e-12f);
    const float npp = fmaxf(sqrtf(vals[1]), 1e-12f);
    const float ps = vals[2] / (na * npp) * 5.0f;  // 1/TEMP
    float S = 0.f;
#pragma unroll
    for (int k = 0; k < NNEG; ++k) S += expf(vals[3 + k] / na * 5.0f);
    lsum += logf(expf(ps) + S) - ps;
  }
  if (l == 0) swsum[w] = lsum;
  __syncthreads();
  if (t == 0) lpart[blockIdx.x] = swsum[0] + swsum[1] + swsum[2] + swsum[3];
}

__global__ void k_final(const float* __restrict__ lpart, float* __restrict__ out) {
  const int t = threadIdx.x;  // 64
  float v = lpart[t] + lpart[t + 64] + lpart[t + 128] + lpart[t + 192];
#pragma unroll
  for (int off = 32; off > 0; off >>= 1) v += __shfl_xor(v, off);
  if (t == 0) out[0] = v * (1.0f / (float)NN);
}

extern "C" void kernel_launch(void* const* d_in, const int* in_sizes, int n_in,
                              void* d_out, int out_size, void* d_ws, size_t ws_size,
                              hipStream_t stream) {
  const float* z = (const float*)d_in[0];
  const float* dm = (const float*)d_in[1];
  // d_in[2] edge_index, d_in[3] reliable_negatives: unused by the forward pass
  const int* neg_idx = (const int*)d_in[4];
  float* out = (float*)d_out;

  // workspace: zp (4MB) | partials bf16 (KS*4MB) | lpart (1KB)
  const size_t ZP = (size_t)NN * DFF * 2;  // 4 MB
  auto need = [ZP](size_t ks) { return ZP + ks * (size_t)NN * DFF * 2 + 1024; };
  int KS = 8;
  if (ws_size < need(8)) KS = (ws_size >= need(4)) ? 4 : 2;

  char* ws = (char*)d_ws;
  unsigned short* zp = (unsigned short*)ws;
  unsigned short* part = (unsigned short*)(ws + ZP);
  float* lpart = (float*)(ws + ZP + (size_t)KS * NN * DFF * 2);

  k_pack<<<dim3(128, 4), 256, 0, stream>>>(z, zp);
  k_gemm<<<64 * KS, 512, 0, stream>>>(dm, zp, part, KS);
  k_loss<<<256, 256, 0, stream>>>(z, part, neg_idx, lpart, KS);
  k_final<<<1, 64, 0, stream>>>(lpart, out);
}

// Round 9
// 136.640 us; speedup vs baseline: 1.1591x; 1.1591x over previous
//
#include <hip/hip_runtime.h>
#include <hip/hip_bf16.h>

// LearnableDiffusionContrastiveLoss on MI355X.
// Algebra: l2norm(dm_normalized @ z) == l2norm(dm @ z) (positive row scaling
// cancels) -> skip the 10-step normalization entirely.
// R9 = R7 (123.6us, conflict-free LDS, contiguous staging) + exactly two
// changes to test the L2-residency theory:
//   (1) ks = blockIdx & (KS-1): round-robin dispatch pins each K-split slice
//       to one XCD -> its 512KB zp slice stays L2-resident (B = L2 hits).
//   (2) dm loads non-temporal: the 256MB stream can't evict the zp slice.
// Everything else is bit-identical to R7.

typedef float f32x4 __attribute__((ext_vector_type(4)));
typedef short s16x8 __attribute__((ext_vector_type(8)));

#define NN 8192
#define DFF 256
#define NNEG 10

__device__ __forceinline__ unsigned short f2bf(float x) {
  return __builtin_bit_cast(unsigned short, __float2bfloat16(x));
}

__device__ __forceinline__ float bf2f(unsigned short u) {
  return __builtin_bit_cast(float, (unsigned int)u << 16);
}

__device__ __forceinline__ void gload_lds16(const void* g, void* l) {
  __builtin_amdgcn_global_load_lds(
      (const __attribute__((address_space(1))) void*)(void*)g,
      (__attribute__((address_space(3))) void*)l, 16, 0, 0);
}

__device__ __forceinline__ float dot4(float4 a, float4 b) {
  return a.x * b.x + a.y * b.y + a.z * b.z + a.w * b.w;
}

// ---- pack z [8192][256] f32 -> zp bf16 [kchunk 256][kw 4][col 256][ke 8] -----
// zp elem offset(k,d) = (k>>5)*8192 + ((k>>3)&3)*2048 + d*8 + (k&7)
// so each GEMM K-step (32 k x 256 d) is one contiguous 16KB chunk.
__global__ void k_pack(const float* __restrict__ z,
                       unsigned short* __restrict__ zp) {
  __shared__ float tile[64][65];
  const int bx = blockIdx.x;  // k tile 0..127
  const int by = blockIdx.y;  // d tile 0..3
  const int t = threadIdx.x;
  const int lc = t & 63, lq = t >> 6;  // 0..3
#pragma unroll
  for (int p = 0; p < 16; ++p) {
    const int kr = lq * 16 + p;
    tile[kr][lc] = z[(size_t)(bx * 64 + kr) * DFF + by * 64 + lc];
  }
  __syncthreads();
#pragma unroll
  for (int p2 = 0; p2 < 2; ++p2) {
    const int ko = lq * 2 + p2;  // k-octet within tile, 0..7
    s16x8 v;
#pragma unroll
    for (int ke = 0; ke < 8; ++ke) v[ke] = (short)f2bf(tile[ko * 8 + ke][lc]);
    const int chunk = bx * 2 + (ko >> 2);
    const int kw = ko & 3;
    const int d = by * 64 + lc;
    *(s16x8*)(zp + (size_t)chunk * 8192 + kw * 2048 + d * 8) = v;
  }
}

// ---- GEMM: part[ks] = dm[mtile, ks-slice] @ z  (BM=128, BN=256, BK=32) -------
// 512 thr / 8 waves, wave (wm,wn) = (w>>2, w&3) owns rows [wm*64,+64) x cols
// [wn*64,+64): 4x4 16x16x32 frags. LDS (dbuf 48KB):
//   sA: [kw 4][row 128][ke 8] bf16 8KB (reg-staged f32->bf16, linear writes)
//   sB: [kw 4][col 256][ke 8] bf16 16KB (= zp chunk, byte-linear gload_lds)
// Frag reads: 16 lanes read 256B contiguous -> conflict-free.
__global__ __launch_bounds__(512, 2) void k_gemm(const float* __restrict__ dm,
                                                 const unsigned short* __restrict__ zp,
                                                 unsigned short* __restrict__ part,
                                                 int KS) {
  __shared__ __align__(16) unsigned short sA[2][4096];  // 2 x 8 KB
  __shared__ __align__(16) unsigned short sB[2][8192];  // 2 x 16 KB
  const int bx = blockIdx.x;
  const int ks = bx & (KS - 1);  // XCD id under round-robin dispatch (KS=8)
  const int mtile = bx / KS;     // 0..63
  const int klen = NN / KS;
  const int k0 = ks * klen;
  const int c0 = k0 >> 5;       // first K-chunk
  const int steps = klen / 32;  // 32 for KS=8
  const int tid = threadIdx.x;
  const int w = tid >> 6;
  const int l = tid & 63;
  const int m0 = mtile * 128;

  // A staging: thread owns 8 consecutive k of one row (2 float4 -> 1 s16x8)
  const int arow = w * 16 + (l & 15);  // 0..127
  const int akw = l >> 4;              // 0..3
  const float* asrc = dm + (size_t)(m0 + arow) * NN + k0 + akw * 8;

  const int r16 = l & 15, kw = l >> 4;
  const int wm = w >> 2, wn = w & 3;

  f32x4 acc[4][4] = {};
  f32x4 a0, a1;

#define LOAD_A(t_)                                                            \
  {                                                                           \
    a0 = __builtin_nontemporal_load((const f32x4*)(asrc + (t_)*32));          \
    a1 = __builtin_nontemporal_load((const f32x4*)(asrc + (t_)*32 + 4));      \
  }

#define WRITE_A(s_)                                                          \
  {                                                                          \
    s16x8 h_;                                                                \
    h_[0] = (short)f2bf(a0[0]); h_[1] = (short)f2bf(a0[1]);                  \
    h_[2] = (short)f2bf(a0[2]); h_[3] = (short)f2bf(a0[3]);                  \
    h_[4] = (short)f2bf(a1[0]); h_[5] = (short)f2bf(a1[1]);                  \
    h_[6] = (short)f2bf(a1[2]); h_[7] = (short)f2bf(a1[3]);                  \
    *(s16x8*)&sA[s_][akw * 1024 + arow * 8] = h_;                            \
  }

#define STAGE_B(t_, s_)                                                      \
  {                                                                          \
    const unsigned short* cs_ = zp + (size_t)(c0 + (t_)) * 8192;             \
    _Pragma("unroll") for (int q = 0; q < 2; ++q) {                          \
      const int piece_ = w * 2 + q; /* 0..15, 1KB each */                    \
      gload_lds16((const char*)(cs_ + piece_ * 512) + l * 16,                \
                  (char*)sB[s_] + piece_ * 1024);                            \
    }                                                                        \
  }

#define COMPUTE(s_)                                                          \
  {                                                                          \
    s16x8 af[4], bfr[4];                                                     \
    _Pragma("unroll") for (int mi = 0; mi < 4; ++mi) {                       \
      const int row_ = wm * 64 + mi * 16 + r16;                              \
      af[mi] = *(const s16x8*)&sA[s_][kw * 1024 + row_ * 8];                 \
    }                                                                        \
    _Pragma("unroll") for (int nj = 0; nj < 4; ++nj) {                       \
      const int col_ = wn * 64 + nj * 16 + r16;                              \
      bfr[nj] = *(const s16x8*)&sB[s_][kw * 2048 + col_ * 8];                \
    }                                                                        \
    _Pragma("unroll") for (int mi = 0; mi < 4; ++mi)                         \
      _Pragma("unroll") for (int nj = 0; nj < 4; ++nj)                       \
        acc[mi][nj] = __builtin_amdgcn_mfma_f32_16x16x32_bf16(               \
            af[mi], bfr[nj], acc[mi][nj], 0, 0, 0);                          \
  }

  // prologue
  STAGE_B(0, 0);
  LOAD_A(0);
  WRITE_A(0);
  __syncthreads();

  for (int t = 0; t < steps; ++t) {
    const int cur = t & 1, nxt = cur ^ 1;
    if (t + 1 < steps) {
      LOAD_A(t + 1);
      STAGE_B(t + 1, nxt);
    }
    COMPUTE(cur);
    if (t + 1 < steps) WRITE_A(nxt);
    __syncthreads();
  }

#undef LOAD_A
#undef WRITE_A
#undef STAGE_B
#undef COMPUTE

  // epilogue: C/D layout col=lane&15, row=(lane>>4)*4+reg [verified m89/m91]
  unsigned short* cb = part + (size_t)ks * NN * DFF;
#pragma unroll
  for (int mi = 0; mi < 4; ++mi)
#pragma unroll
    for (int nj = 0; nj < 4; ++nj) {
      const int col = wn * 64 + nj * 16 + r16;
      const int row0 = m0 + wm * 64 + mi * 16 + kw * 4;
#pragma unroll
      for (int r = 0; r < 4; ++r)
        cb[(size_t)(row0 + r) * DFF + col] = f2bf(acc[mi][nj][r]);
    }
}

// ---- fused loss: neg norms, K-split partial sum (bf16), norms, LSE -----------
__global__ __launch_bounds__(256) void k_loss(const float* __restrict__ z,
                                              const unsigned short* __restrict__ part,
                                              const int* __restrict__ neg_idx,
                                              float* __restrict__ lpart, int KS) {
  __shared__ float sneg[NNEG * DFF];
  __shared__ float swsum[4];
  const int t = threadIdx.x;
  const int w = t >> 6, l = t & 63;
  for (int k = w; k < NNEG; k += 4) {
    const int idx = neg_idx[k];
    float4 v = *(const float4*)(z + (size_t)idx * DFF + l * 4);
    float ss = dot4(v, v);
#pragma unroll
    for (int off = 32; off > 0; off >>= 1) ss += __shfl_xor(ss, off);
    const float s = 1.0f / fmaxf(sqrtf(ss), 1e-12f);
    float4 o;
    o.x = v.x * s; o.y = v.y * s; o.z = v.z * s; o.w = v.w * s;
    *(float4*)&sneg[k * DFF + l * 4] = o;
  }
  __syncthreads();
  const int gw = blockIdx.x * 4 + w;  // 0..1023, 8 rows each
  float lsum = 0.f;
  for (int rr = 0; rr < 8; ++rr) {
    const int i = gw * 8 + rr;
    const float4 a = *(const float4*)(z + (size_t)i * DFF + l * 4);
    float4 p; p.x = 0.f; p.y = 0.f; p.z = 0.f; p.w = 0.f;
    for (int ksp = 0; ksp < KS; ++ksp) {
      const ushort4 q =
          *(const ushort4*)(part + ((size_t)ksp * NN + i) * DFF + l * 4);
      p.x += bf2f(q.x); p.y += bf2f(q.y); p.z += bf2f(q.z); p.w += bf2f(q.w);
    }
    float vals[13];
    vals[0] = dot4(a, a);
    vals[1] = dot4(p, p);
    vals[2] = dot4(a, p);
#pragma unroll
    for (int k = 0; k < NNEG; ++k) {
      const float4 nv = *(const float4*)&sneg[k * DFF + l * 4];
      vals[3 + k] = dot4(a, nv);
    }
#pragma unroll
    for (int off = 32; off > 0; off >>= 1)
#pragma unroll
      for (int j = 0; j < 13; ++j) vals[j] += __shfl_xor(vals[j], off);
    const float na = fmaxf(sqrtf(vals[0]), 1e-12f);
    const float npp = fmaxf(sqrtf(vals[1]), 1e-12f);
    const float ps = vals[2] / (na * npp) * 5.0f;  // 1/TEMP
    float S = 0.f;
#pragma unroll
    for (int k = 0; k < NNEG; ++k) S += expf(vals[3 + k] / na * 5.0f);
    lsum += logf(expf(ps) + S) - ps;
  }
  if (l == 0) swsum[w] = lsum;
  __syncthreads();
  if (t == 0) lpart[blockIdx.x] = swsum[0] + swsum[1] + swsum[2] + swsum[3];
}

__global__ void k_final(const float* __restrict__ lpart, float* __restrict__ out) {
  const int t = threadIdx.x;  // 64
  float v = lpart[t] + lpart[t + 64] + lpart[t + 128] + lpart[t + 192];
#pragma unroll
  for (int off = 32; off > 0; off >>= 1) v += __shfl_xor(v, off);
  if (t == 0) out[0] = v * (1.0f / (float)NN);
}

extern "C" void kernel_launch(void* const* d_in, const int* in_sizes, int n_in,
                              void* d_out, int out_size, void* d_ws, size_t ws_size,
                              hipStream_t stream) {
  const float* z = (const float*)d_in[0];
  const float* dm = (const float*)d_in[1];
  // d_in[2] edge_index, d_in[3] reliable_negatives: unused by the forward pass
  const int* neg_idx = (const int*)d_in[4];
  float* out = (float*)d_out;

  // workspace: zp (4MB) | partials bf16 (KS*4MB) | lpart (1KB)
  const size_t ZP = (size_t)NN * DFF * 2;  // 4 MB
  auto need = [ZP](size_t ks) { return ZP + ks * (size_t)NN * DFF * 2 + 1024; };
  int KS = 8;
  if (ws_size < need(8)) KS = (ws_size >= need(4)) ? 4 : 2;

  char* ws = (char*)d_ws;
  unsigned short* zp = (unsigned short*)ws;
  unsigned short* part = (unsigned short*)(ws + ZP);
  float* lpart = (float*)(ws + ZP + (size_t)KS * NN * DFF * 2);

  k_pack<<<dim3(128, 4), 256, 0, stream>>>(z, zp);
  k_gemm<<<64 * KS, 512, 0, stream>>>(dm, zp, part, KS);
  k_loss<<<256, 256, 0, stream>>>(z, part, neg_idx, lpart, KS);
  k_final<<<1, 64, 0, stream>>>(lpart, out);
}

// Round 10
// 130.855 us; speedup vs baseline: 1.2103x; 1.0442x over previous
//
#include <hip/hip_runtime.h>
#include <hip/hip_bf16.h>

// LearnableDiffusionContrastiveLoss on MI355X.
// Algebra: l2norm(dm_normalized @ z) == l2norm(dm @ z) (positive row scaling
// cancels) -> skip the 10-step normalization entirely.
// R10: staged-traffic minimization under the measured ~5.5 TB/s staging
// plateau. BM=256 (B staged 256->128 MB), grid = 32 mtiles x KS8 = 256 blocks
// = 1/CU, ks = bx&7 pins one K-split slice per XCD (512KB zp slice stays
// L2-resident -> B off the slow path). R7's conflict-free LDS layouts kept
// verbatim. No nontemporal anywhere (R9 lesson).

typedef float f32x4 __attribute__((ext_vector_type(4)));
typedef short s16x8 __attribute__((ext_vector_type(8)));

#define NN 8192
#define DFF 256
#define NNEG 10

__device__ __forceinline__ unsigned short f2bf(float x) {
  return __builtin_bit_cast(unsigned short, __float2bfloat16(x));
}

__device__ __forceinline__ float bf2f(unsigned short u) {
  return __builtin_bit_cast(float, (unsigned int)u << 16);
}

__device__ __forceinline__ void gload_lds16(const void* g, void* l) {
  __builtin_amdgcn_global_load_lds(
      (const __attribute__((address_space(1))) void*)(void*)g,
      (__attribute__((address_space(3))) void*)l, 16, 0, 0);
}

__device__ __forceinline__ float dot4(float4 a, float4 b) {
  return a.x * b.x + a.y * b.y + a.z * b.z + a.w * b.w;
}

// ---- pack z [8192][256] f32 -> zp bf16 [kchunk 256][kw 4][col 256][ke 8] -----
// zp elem offset(k,d) = (k>>5)*8192 + ((k>>3)&3)*2048 + d*8 + (k&7)
// so each GEMM K-step (32 k x 256 d) is one contiguous 16KB chunk.
__global__ void k_pack(const float* __restrict__ z,
                       unsigned short* __restrict__ zp) {
  __shared__ float tile[64][65];
  const int bx = blockIdx.x;  // k tile 0..127
  const int by = blockIdx.y;  // d tile 0..3
  const int t = threadIdx.x;
  const int lc = t & 63, lq = t >> 6;  // 0..3
#pragma unroll
  for (int p = 0; p < 16; ++p) {
    const int kr = lq * 16 + p;
    tile[kr][lc] = z[(size_t)(bx * 64 + kr) * DFF + by * 64 + lc];
  }
  __syncthreads();
#pragma unroll
  for (int p2 = 0; p2 < 2; ++p2) {
    const int ko = lq * 2 + p2;  // k-octet within tile, 0..7
    s16x8 v;
#pragma unroll
    for (int ke = 0; ke < 8; ++ke) v[ke] = (short)f2bf(tile[ko * 8 + ke][lc]);
    const int chunk = bx * 2 + (ko >> 2);
    const int kw = ko & 3;
    const int d = by * 64 + lc;
    *(s16x8*)(zp + (size_t)chunk * 8192 + kw * 2048 + d * 8) = v;
  }
}

// ---- GEMM: part[ks] = dm[mtile, ks-slice] @ z  (BM=256, BN=256, BK=32) -------
// 1024 thr / 16 waves, wave (wm,wn) = (w>>2, w&3) owns rows [wm*64,+64) x cols
// [wn*64,+64): 4x4 16x16x32 frags. LDS (dbuf 64KB):
//   sA: [kw 4][row 256][ke 8] bf16 16KB (reg-staged f32->bf16, min-bank writes)
//   sB: [kw 4][col 256][ke 8] bf16 16KB (= zp chunk, byte-linear gload_lds)
// All wave LDS ops move contiguous 256B per 16-lane group -> min words/bank.
__global__ __launch_bounds__(1024, 1) void k_gemm(const float* __restrict__ dm,
                                                  const unsigned short* __restrict__ zp,
                                                  unsigned short* __restrict__ part,
                                                  int KS) {
  __shared__ __align__(16) unsigned short sA[2][8192];  // 2 x 16 KB
  __shared__ __align__(16) unsigned short sB[2][8192];  // 2 x 16 KB
  const int bx = blockIdx.x;
  const int ks = bx & (KS - 1);  // XCD id under round-robin dispatch (KS=8)
  const int mtile = bx / KS;     // 0..31
  const int klen = NN / KS;
  const int k0 = ks * klen;
  const int c0 = k0 >> 5;       // first K-chunk
  const int steps = klen / 32;  // 32 for KS=8
  const int tid = threadIdx.x;
  const int w = tid >> 6;       // 0..15
  const int l = tid & 63;
  const int m0 = mtile * 256;

  // A staging: thread owns 8 consecutive k of one row (2 float4 -> 1 s16x8)
  const int arow = tid >> 2;  // 0..255
  const int akw = tid & 3;    // 0..3
  const float* asrc = dm + (size_t)(m0 + arow) * NN + k0 + akw * 8;

  const int r16 = l & 15, kw = l >> 4;
  const int wm = w >> 2, wn = w & 3;

  f32x4 acc[4][4] = {};
  f32x4 a0, a1;

#define LOAD_A(t_)                                                           \
  {                                                                          \
    a0 = *(const f32x4*)(asrc + (t_)*32);                                    \
    a1 = *(const f32x4*)(asrc + (t_)*32 + 4);                                \
  }

#define WRITE_A(s_)                                                         \
  {                                                                         \
    s16x8 h_;                                                               \
    h_[0] = (short)f2bf(a0[0]); h_[1] = (short)f2bf(a0[1]);                 \
    h_[2] = (short)f2bf(a0[2]); h_[3] = (short)f2bf(a0[3]);                 \
    h_[4] = (short)f2bf(a1[0]); h_[5] = (short)f2bf(a1[1]);                 \
    h_[6] = (short)f2bf(a1[2]); h_[7] = (short)f2bf(a1[3]);                 \
    *(s16x8*)&sA[s_][akw * 2048 + arow * 8] = h_;                           \
  }

#define STAGE_B(t_, s_)                                                     \
  {                                                                         \
    const unsigned short* cs_ = zp + (size_t)(c0 + (t_)) * 8192;            \
    gload_lds16((const char*)(cs_ + w * 512) + l * 16,                      \
                (char*)sB[s_] + w * 1024);                                  \
  }

#define COMPUTE(s_)                                                         \
  {                                                                         \
    s16x8 af[4], bfr[4];                                                    \
    _Pragma("unroll") for (int mi = 0; mi < 4; ++mi) {                      \
      const int row_ = wm * 64 + mi * 16 + r16;                             \
      af[mi] = *(const s16x8*)&sA[s_][kw * 2048 + row_ * 8];                \
    }                                                                       \
    _Pragma("unroll") for (int nj = 0; nj < 4; ++nj) {                      \
      const int col_ = wn * 64 + nj * 16 + r16;                             \
      bfr[nj] = *(const s16x8*)&sB[s_][kw * 2048 + col_ * 8];               \
    }                                                                       \
    _Pragma("unroll") for (int mi = 0; mi < 4; ++mi)                        \
      _Pragma("unroll") for (int nj = 0; nj < 4; ++nj)                      \
        acc[mi][nj] = __builtin_amdgcn_mfma_f32_16x16x32_bf16(              \
            af[mi], bfr[nj], acc[mi][nj], 0, 0, 0);                         \
  }

  // prologue
  STAGE_B(0, 0);
  LOAD_A(0);
  WRITE_A(0);
  __syncthreads();

  for (int t = 0; t < steps; ++t) {
    const int cur = t & 1, nxt = cur ^ 1;
    if (t + 1 < steps) {
      LOAD_A(t + 1);
      STAGE_B(t + 1, nxt);
    }
    COMPUTE(cur);
    if (t + 1 < steps) WRITE_A(nxt);
    __syncthreads();
  }

#undef LOAD_A
#undef WRITE_A
#undef STAGE_B
#undef COMPUTE

  // epilogue: C/D layout col=lane&15, row=(lane>>4)*4+reg [verified m89/m91]
  unsigned short* cb = part + (size_t)ks * NN * DFF;
#pragma unroll
  for (int mi = 0; mi < 4; ++mi)
#pragma unroll
    for (int nj = 0; nj < 4; ++nj) {
      const int col = wn * 64 + nj * 16 + r16;
      const int row0 = m0 + wm * 64 + mi * 16 + kw * 4;
#pragma unroll
      for (int r = 0; r < 4; ++r)
        cb[(size_t)(row0 + r) * DFF + col] = f2bf(acc[mi][nj][r]);
    }
}

// ---- fused loss: neg norms, K-split partial sum (bf16), norms, LSE -----------
__global__ __launch_bounds__(256) void k_loss(const float* __restrict__ z,
                                              const unsigned short* __restrict__ part,
                                              const int* __restrict__ neg_idx,
                                              float* __restrict__ lpart, int KS) {
  __shared__ float sneg[NNEG * DFF];
  __shared__ float swsum[4];
  const int t = threadIdx.x;
  const int w = t >> 6, l = t & 63;
  for (int k = w; k < NNEG; k += 4) {
    const int idx = neg_idx[k];
    float4 v = *(const float4*)(z + (size_t)idx * DFF + l * 4);
    float ss = dot4(v, v);
#pragma unroll
    for (int off = 32; off > 0; off >>= 1) ss += __shfl_xor(ss, off);
    const float s = 1.0f / fmaxf(sqrtf(ss), 1e-12f);
    float4 o;
    o.x = v.x * s; o.y = v.y * s; o.z = v.z * s; o.w = v.w * s;
    *(float4*)&sneg[k * DFF + l * 4] = o;
  }
  __syncthreads();
  const int gw = blockIdx.x * 4 + w;  // 0..1023, 8 rows each
  float lsum = 0.f;
  for (int rr = 0; rr < 8; ++rr) {
    const int i = gw * 8 + rr;
    const float4 a = *(const float4*)(z + (size_t)i * DFF + l * 4);
    float4 p; p.x = 0.f; p.y = 0.f; p.z = 0.f; p.w = 0.f;
    for (int ksp = 0; ksp < KS; ++ksp) {
      const ushort4 q =
          *(const ushort4*)(part + ((size_t)ksp * NN + i) * DFF + l * 4);
      p.x += bf2f(q.x); p.y += bf2f(q.y); p.z += bf2f(q.z); p.w += bf2f(q.w);
    }
    float vals[13];
    vals[0] = dot4(a, a);
    vals[1] = dot4(p, p);
    vals[2] = dot4(a, p);
#pragma unroll
    for (int k = 0; k < NNEG; ++k) {
      const float4 nv = *(const float4*)&sneg[k * DFF + l * 4];
      vals[3 + k] = dot4(a, nv);
    }
#pragma unroll
    for (int off = 32; off > 0; off >>= 1)
#pragma unroll
      for (int j = 0; j < 13; ++j) vals[j] += __shfl_xor(vals[j], off);
    const float na = fmaxf(sqrtf(vals[0]), 1e-12f);
    const float npp = fmaxf(sqrtf(vals[1]), 1e-12f);
    const float ps = vals[2] / (na * npp) * 5.0f;  // 1/TEMP
    float S = 0.f;
#pragma unroll
    for (int k = 0; k < NNEG; ++k) S += expf(vals[3 + k] / na * 5.0f);
    lsum += logf(expf(ps) + S) - ps;
  }
  if (l == 0) swsum[w] = lsum;
  __syncthreads();
  if (t == 0) lpart[blockIdx.x] = swsum[0] + swsum[1] + swsum[2] + swsum[3];
}

__global__ void k_final(const float* __restrict__ lpart, float* __restrict__ out) {
  const int t = threadIdx.x;  // 64
  float v = lpart[t] + lpart[t + 64] + lpart[t + 128] + lpart[t + 192];
#pragma unroll
  for (int off = 32; off > 0; off >>= 1) v += __shfl_xor(v, off);
  if (t == 0) out[0] = v * (1.0f / (float)NN);
}

extern "C" void kernel_launch(void* const* d_in, const int* in_sizes, int n_in,
                              void* d_out, int out_size, void* d_ws, size_t ws_size,
                              hipStream_t stream) {
  const float* z = (const float*)d_in[0];
  const float* dm = (const float*)d_in[1];
  // d_in[2] edge_index, d_in[3] reliable_negatives: unused by the forward pass
  const int* neg_idx = (const int*)d_in[4];
  float* out = (float*)d_out;

  // workspace: zp (4MB) | partials bf16 (KS*4MB) | lpart (1KB)
  const size_t ZP = (size_t)NN * DFF * 2;  // 4 MB
  auto need = [ZP](size_t ks) { return ZP + ks * (size_t)NN * DFF * 2 + 1024; };
  int KS = 8;
  if (ws_size < need(8)) KS = (ws_size >= need(4)) ? 4 : 2;

  char* ws = (char*)d_ws;
  unsigned short* zp = (unsigned short*)ws;
  unsigned short* part = (unsigned short*)(ws + ZP);
  float* lpart = (float*)(ws + ZP + (size_t)KS * NN * DFF * 2);

  k_pack<<<dim3(128, 4), 256, 0, stream>>>(z, zp);
  k_gemm<<<32 * KS, 1024, 0, stream>>>(dm, zp, part, KS);
  k_loss<<<256, 256, 0, stream>>>(z, part, neg_idx, lpart, KS);
  k_final<<<1, 64, 0, stream>>>(lpart, out);
}

// Round 11
// 127.485 us; speedup vs baseline: 1.2423x; 1.0264x over previous
//
#include <hip/hip_runtime.h>
#include <hip/hip_bf16.h>

// LearnableDiffusionContrastiveLoss on MI355X.
// Algebra: l2norm(dm_normalized @ z) == l2norm(dm @ z) (positive row scaling
// cancels) -> skip the 10-step normalization entirely.
// R11 = R7 (123.6us baseline) + hardware-verified XCD-local K-split:
// each block reads its real XCD id (s_getreg HW_REG_XCC_ID, m09) and claims
// (mtile, ks=xcd) from per-slice atomic counters -> every XCD re-reads ONLY
// its 512KB zp slice (L2-resident), removing B's 256MB from the ~6 TB/s
// L3->L2 path. A (256MB f32 dm) stays, compulsory. No other changes.

typedef float f32x4 __attribute__((ext_vector_type(4)));
typedef short s16x8 __attribute__((ext_vector_type(8)));

#define NN 8192
#define DFF 256
#define NNEG 10

__device__ __forceinline__ unsigned short f2bf(float x) {
  return __builtin_bit_cast(unsigned short, __float2bfloat16(x));
}

__device__ __forceinline__ float bf2f(unsigned short u) {
  return __builtin_bit_cast(float, (unsigned int)u << 16);
}

__device__ __forceinline__ void gload_lds16(const void* g, void* l) {
  __builtin_amdgcn_global_load_lds(
      (const __attribute__((address_space(1))) void*)(void*)g,
      (__attribute__((address_space(3))) void*)l, 16, 0, 0);
}

__device__ __forceinline__ float dot4(float4 a, float4 b) {
  return a.x * b.x + a.y * b.y + a.z * b.z + a.w * b.w;
}

// ---- pack z [8192][256] f32 -> zp bf16 [kchunk 256][kw 4][col 256][ke 8] -----
// zp elem offset(k,d) = (k>>5)*8192 + ((k>>3)&3)*2048 + d*8 + (k&7)
// so each GEMM K-step (32 k x 256 d) is one contiguous 16KB chunk.
// Also zeroes the work-claim counters (used by k_gemm, stream-ordered after).
__global__ void k_pack(const float* __restrict__ z,
                       unsigned short* __restrict__ zp,
                       unsigned int* __restrict__ cnt) {
  if (blockIdx.x == 0 && blockIdx.y == 0 && threadIdx.x < 16)
    cnt[threadIdx.x] = 0u;
  __shared__ float tile[64][65];
  const int bx = blockIdx.x;  // k tile 0..127
  const int by = blockIdx.y;  // d tile 0..3
  const int t = threadIdx.x;
  const int lc = t & 63, lq = t >> 6;  // 0..3
#pragma unroll
  for (int p = 0; p < 16; ++p) {
    const int kr = lq * 16 + p;
    tile[kr][lc] = z[(size_t)(bx * 64 + kr) * DFF + by * 64 + lc];
  }
  __syncthreads();
#pragma unroll
  for (int p2 = 0; p2 < 2; ++p2) {
    const int ko = lq * 2 + p2;  // k-octet within tile, 0..7
    s16x8 v;
#pragma unroll
    for (int ke = 0; ke < 8; ++ke) v[ke] = (short)f2bf(tile[ko * 8 + ke][lc]);
    const int chunk = bx * 2 + (ko >> 2);
    const int kw = ko & 3;
    const int d = by * 64 + lc;
    *(s16x8*)(zp + (size_t)chunk * 8192 + kw * 2048 + d * 8) = v;
  }
}

// ---- GEMM: part[ks] = dm[mtile, ks-slice] @ z  (BM=128, BN=256, BK=32) -------
// 512 thr / 8 waves, wave (wm,wn) = (w>>2, w&3) owns rows [wm*64,+64) x cols
// [wn*64,+64): 4x4 16x16x32 frags. LDS (dbuf 48KB):
//   sA: [kw 4][row 128][ke 8] bf16 8KB (reg-staged f32->bf16, linear writes)
//   sB: [kw 4][col 256][ke 8] bf16 16KB (= zp chunk, byte-linear gload_lds)
// Work claiming: ks = this block's XCD (so the 512KB zp slice is L2-local),
// mtile = per-slice atomic ordinal. Pigeonhole-safe spill to neighbor slices
// guarantees each (mtile,ks) pair is claimed exactly once -> deterministic.
__global__ __launch_bounds__(512, 2) void k_gemm(const float* __restrict__ dm,
                                                 const unsigned short* __restrict__ zp,
                                                 unsigned short* __restrict__ part,
                                                 unsigned int* __restrict__ cnt,
                                                 int KS) {
  __shared__ __align__(16) unsigned short sA[2][4096];  // 2 x 8 KB
  __shared__ __align__(16) unsigned short sB[2][8192];  // 2 x 16 KB
  __shared__ int s_mt, s_ks;
  if (threadIdx.x == 0) {
    unsigned int xcc;
    asm volatile("s_getreg_b32 %0, hwreg(HW_REG_XCC_ID)" : "=s"(xcc));
    xcc &= 7u;
    int mt = 0, kk = 0;
    for (int tr = 0; tr < 8; ++tr) {
      const int k2 = (int)((xcc + (unsigned)tr) % (unsigned)KS);
      const unsigned int o = atomicAdd(&cnt[k2], 1u);
      if (o < 64u) { mt = (int)o; kk = k2; break; }
    }
    s_mt = mt;
    s_ks = kk;
  }
  __syncthreads();
  const int mtile = s_mt;  // 0..63
  const int ks = s_ks;     // 0..KS-1 (== this XCD, barring spill)
  const int klen = NN / KS;
  const int k0 = ks * klen;
  const int c0 = k0 >> 5;       // first K-chunk
  const int steps = klen / 32;  // 32 for KS=8
  const int tid = threadIdx.x;
  const int w = tid >> 6;
  const int l = tid & 63;
  const int m0 = mtile * 128;

  // A staging: thread owns 8 consecutive k of one row (2 float4 -> 1 s16x8)
  const int arow = w * 16 + (l & 15);  // 0..127
  const int akw = l >> 4;              // 0..3
  const float* asrc = dm + (size_t)(m0 + arow) * NN + k0 + akw * 8;

  const int r16 = l & 15, kw = l >> 4;
  const int wm = w >> 2, wn = w & 3;

  f32x4 acc[4][4] = {};
  f32x4 a0, a1;

#define LOAD_A(t_)                                                           \
  {                                                                          \
    a0 = *(const f32x4*)(asrc + (t_)*32);                                    \
    a1 = *(const f32x4*)(asrc + (t_)*32 + 4);                                \
  }

#define WRITE_A(s_)                                                         \
  {                                                                         \
    s16x8 h_;                                                               \
    h_[0] = (short)f2bf(a0[0]); h_[1] = (short)f2bf(a0[1]);                 \
    h_[2] = (short)f2bf(a0[2]); h_[3] = (short)f2bf(a0[3]);                 \
    h_[4] = (short)f2bf(a1[0]); h_[5] = (short)f2bf(a1[1]);                 \
    h_[6] = (short)f2bf(a1[2]); h_[7] = (short)f2bf(a1[3]);                 \
    *(s16x8*)&sA[s_][akw * 1024 + arow * 8] = h_;                           \
  }

#define STAGE_B(t_, s_)                                                     \
  {                                                                         \
    const unsigned short* cs_ = zp + (size_t)(c0 + (t_)) * 8192;            \
    _Pragma("unroll") for (int q = 0; q < 2; ++q) {                         \
      const int piece_ = w * 2 + q; /* 0..15, 1KB each */                   \
      gload_lds16((const char*)(cs_ + piece_ * 512) + l * 16,               \
                  (char*)sB[s_] + piece_ * 1024);                           \
    }                                                                       \
  }

#define COMPUTE(s_)                                                         \
  {                                                                         \
    s16x8 af[4], bfr[4];                                                    \
    _Pragma("unroll") for (int mi = 0; mi < 4; ++mi) {                      \
      const int row_ = wm * 64 + mi * 16 + r16;                             \
      af[mi] = *(const s16x8*)&sA[s_][kw * 1024 + row_ * 8];                \
    }                                                                       \
    _Pragma("unroll") for (int nj = 0; nj < 4; ++nj) {                      \
      const int col_ = wn * 64 + nj * 16 + r16;                             \
      bfr[nj] = *(const s16x8*)&sB[s_][kw * 2048 + col_ * 8];               \
    }                                                                       \
    _Pragma("unroll") for (int mi = 0; mi < 4; ++mi)                        \
      _Pragma("unroll") for (int nj = 0; nj < 4; ++nj)                      \
        acc[mi][nj] = __builtin_amdgcn_mfma_f32_16x16x32_bf16(              \
            af[mi], bfr[nj], acc[mi][nj], 0, 0, 0);                         \
  }

  // prologue
  STAGE_B(0, 0);
  LOAD_A(0);
  WRITE_A(0);
  __syncthreads();

  for (int t = 0; t < steps; ++t) {
    const int cur = t & 1, nxt = cur ^ 1;
    if (t + 1 < steps) {
      LOAD_A(t + 1);
      STAGE_B(t + 1, nxt);
    }
    COMPUTE(cur);
    if (t + 1 < steps) WRITE_A(nxt);
    __syncthreads();
  }

#undef LOAD_A
#undef WRITE_A
#undef STAGE_B
#undef COMPUTE

  // epilogue: C/D layout col=lane&15, row=(lane>>4)*4+reg [verified m89/m91]
  unsigned short* cb = part + (size_t)ks * NN * DFF;
#pragma unroll
  for (int mi = 0; mi < 4; ++mi)
#pragma unroll
    for (int nj = 0; nj < 4; ++nj) {
      const int col = wn * 64 + nj * 16 + r16;
      const int row0 = m0 + wm * 64 + mi * 16 + kw * 4;
#pragma unroll
      for (int r = 0; r < 4; ++r)
        cb[(size_t)(row0 + r) * DFF + col] = f2bf(acc[mi][nj][r]);
    }
}

// ---- fused loss: neg norms, K-split partial sum (bf16), norms, LSE -----------
__global__ __launch_bounds__(256) void k_loss(const float* __restrict__ z,
                                              const unsigned short* __restrict__ part,
                                              const int* __restrict__ neg_idx,
                                              float* __restrict__ lpart, int KS) {
  __shared__ float sneg[NNEG * DFF];
  __shared__ float swsum[4];
  const int t = threadIdx.x;
  const int w = t >> 6, l = t & 63;
  for (int k = w; k < NNEG; k += 4) {
    const int idx = neg_idx[k];
    float4 v = *(const float4*)(z + (size_t)idx * DFF + l * 4);
    float ss = dot4(v, v);
#pragma unroll
    for (int off = 32; off > 0; off >>= 1) ss += __shfl_xor(ss, off);
    const float s = 1.0f / fmaxf(sqrtf(ss), 1e-12f);
    float4 o;
    o.x = v.x * s; o.y = v.y * s; o.z = v.z * s; o.w = v.w * s;
    *(float4*)&sneg[k * DFF + l * 4] = o;
  }
  __syncthreads();
  const int gw = blockIdx.x * 4 + w;  // 0..1023, 8 rows each
  float lsum = 0.f;
  for (int rr = 0; rr < 8; ++rr) {
    const int i = gw * 8 + rr;
    const float4 a = *(const float4*)(z + (size_t)i * DFF + l * 4);
    float4 p; p.x = 0.f; p.y = 0.f; p.z = 0.f; p.w = 0.f;
    for (int ksp = 0; ksp < KS; ++ksp) {
      const ushort4 q =
          *(const ushort4*)(part + ((size_t)ksp * NN + i) * DFF + l * 4);
      p.x += bf2f(q.x); p.y += bf2f(q.y); p.z += bf2f(q.z); p.w += bf2f(q.w);
    }
    float vals[13];
    vals[0] = dot4(a, a);
    vals[1] = dot4(p, p);
    vals[2] = dot4(a, p);
#pragma unroll
    for (int k = 0; k < NNEG; ++k) {
      const float4 nv = *(const float4*)&sneg[k * DFF + l * 4];
      vals[3 + k] = dot4(a, nv);
    }
#pragma unroll
    for (int off = 32; off > 0; off >>= 1)
#pragma unroll
      for (int j = 0; j < 13; ++j) vals[j] += __shfl_xor(vals[j], off);
    const float na = fmaxf(sqrtf(vals[0]), 1e-12f);
    const float npp = fmaxf(sqrtf(vals[1]), 1e-12f);
    const float ps = vals[2] / (na * npp) * 5.0f;  // 1/TEMP
    float S = 0.f;
#pragma unroll
    for (int k = 0; k < NNEG; ++k) S += expf(vals[3 + k] / na * 5.0f);
    lsum += logf(expf(ps) + S) - ps;
  }
  if (l == 0) swsum[w] = lsum;
  __syncthreads();
  if (t == 0) lpart[blockIdx.x] = swsum[0] + swsum[1] + swsum[2] + swsum[3];
}

__global__ void k_final(const float* __restrict__ lpart, float* __restrict__ out) {
  const int t = threadIdx.x;  // 64
  float v = lpart[t] + lpart[t + 64] + lpart[t + 128] + lpart[t + 192];
#pragma unroll
  for (int off = 32; off > 0; off >>= 1) v += __shfl_xor(v, off);
  if (t == 0) out[0] = v * (1.0f / (float)NN);
}

extern "C" void kernel_launch(void* const* d_in, const int* in_sizes, int n_in,
                              void* d_out, int out_size, void* d_ws, size_t ws_size,
                              hipStream_t stream) {
  const float* z = (const float*)d_in[0];
  const float* dm = (const float*)d_in[1];
  // d_in[2] edge_index, d_in[3] reliable_negatives: unused by the forward pass
  const int* neg_idx = (const int*)d_in[4];
  float* out = (float*)d_out;

  // workspace: zp (4MB) | partials bf16 (KS*4MB) | lpart (1KB) | cnt (64B)
  const size_t ZP = (size_t)NN * DFF * 2;  // 4 MB
  auto need = [ZP](size_t ks) {
    return ZP + ks * (size_t)NN * DFF * 2 + 1024 + 64;
  };
  int KS = 8;
  if (ws_size < need(8)) KS = (ws_size >= need(4)) ? 4 : 2;

  char* ws = (char*)d_ws;
  unsigned short* zp = (unsigned short*)ws;
  unsigned short* part = (unsigned short*)(ws + ZP);
  float* lpart = (float*)(ws + ZP + (size_t)KS * NN * DFF * 2);
  unsigned int* cnt = (unsigned int*)(ws + ZP + (size_t)KS * NN * DFF * 2 + 1024);

  k_pack<<<dim3(128, 4), 256, 0, stream>>>(z, zp, cnt);
  k_gemm<<<64 * KS, 512, 0, stream>>>(dm, zp, part, cnt, KS);
  k_loss<<<256, 256, 0, stream>>>(z, part, neg_idx, lpart, KS);
  k_final<<<1, 64, 0, stream>>>(lpart, out);
}